// Round 7
// baseline (2512.511 us; speedup 1.0000x reference)
//
#include <hip/hip_runtime.h>

// Problem constants
#define B_ 32
#define S_ 2048
#define DA 32
#define DH 128
#define DS 64
#define DS2 4096
#define TKK 16

template <int CTRL>
__device__ __forceinline__ float dpp_add(float x) {
  int t = __builtin_amdgcn_update_dpp(0, __float_as_int(x), CTRL, 0xF, 0xF, true);
  return x + __int_as_float(t);
}
// sum over the 16 lanes of each row, result uniform within the row
__device__ __forceinline__ float row_sum16(float x) {
  x = dpp_add<0xB1>(x);
  x = dpp_add<0x4E>(x);
  x = dpp_add<0x141>(x);
  x = dpp_add<0x140>(x);
  return x;
}

// async global->LDS DMA, 16 B per lane (dest = wave-uniform base + lane*16)
__device__ __forceinline__ void gl2lds16(const float* g, float* l) {
  __builtin_amdgcn_global_load_lds(
      (const __attribute__((address_space(1))) void*)g,
      (__attribute__((address_space(3))) void*)l, 16, 0, 0);
}

// ---------------------------------------------------------------------------
// Shared-memory union, <= 64.1 KB -> TWO blocks per CU (the one structural
// axis R0-R6 never moved: all six invariant ~103us variants had 1 block/CU,
// so every co-resident wave shared one barrier schedule. Two independent
// blocks/CU let block B's FMAs fill block A's stalls -- m114 overlap).
// RNN ring shrunk 6->4 slots (96->64 KB) to fit; producer stride 3 < depth 4
// so the flag/gate protocol remains deadlock-free.
// ---------------------------------------------------------------------------
struct SharedRnn {
  float4 ring[4][16][64];   // 64 KB
  int flags[4];
  int cons;
};
struct SharedGemm {
  float As[2][TKK][128];    // 16 KB
  float Bs[2][TKK][128];    // 16 KB
};
struct SharedMlp {
  float a_t[DA][64];        // 8 KB
  float w0_l[DA][DH];       // 16 KB
  float h0t[DH][64];        // 32 KB
};
union SharedU {
  SharedRnn r;
  SharedGemm g;
  SharedMlp m;
};

// ---------------------------------------------------------------------------
// MLP tile (R0-validated 256-thread body): 64 tokens -> h1t[f][tok]
// ---------------------------------------------------------------------------
__device__ __forceinline__ void mlp_tile(
    const float* __restrict__ actions, const float* __restrict__ w0,
    const float* __restrict__ b0, const float* __restrict__ w1,
    const float* __restrict__ b1, float* __restrict__ h1t,
    int s_base, int M, int m0, SharedMlp& sm, int tid)
{
#pragma unroll
  for (int q = 0; q < 2; ++q) {
    int g = tid + 256 * q;
    int tok = g >> 3, kq = g & 7;
    int tl = m0 + tok;
    int b = tl & 31, s = s_base + (tl >> 5);
    float4 v = *(const float4*)(actions + ((size_t)b * S_ + s) * DA + 4 * kq);
    sm.a_t[4 * kq + 0][tok] = v.x; sm.a_t[4 * kq + 1][tok] = v.y;
    sm.a_t[4 * kq + 2][tok] = v.z; sm.a_t[4 * kq + 3][tok] = v.w;
  }
#pragma unroll
  for (int q = 0; q < 4; ++q) {
    int g = tid + 256 * q;
    ((float4*)&sm.w0_l[0][0])[g] = ((const float4*)w0)[g];
  }
  __syncthreads();

  const int tm = tid & 15;
  const int tn = tid >> 4;

  float acc[4][8];
#pragma unroll
  for (int mi = 0; mi < 4; ++mi)
#pragma unroll
    for (int ni = 0; ni < 8; ++ni) acc[mi][ni] = 0.f;

#pragma unroll 4
  for (int k = 0; k < DA; ++k) {
    float4 a4 = *(const float4*)&sm.a_t[k][4 * tm];
    float4 wa = *(const float4*)&sm.w0_l[k][8 * tn];
    float4 wb = *(const float4*)&sm.w0_l[k][8 * tn + 4];
    float av[4] = {a4.x, a4.y, a4.z, a4.w};
    float wv[8] = {wa.x, wa.y, wa.z, wa.w, wb.x, wb.y, wb.z, wb.w};
#pragma unroll
    for (int mi = 0; mi < 4; ++mi)
#pragma unroll
      for (int ni = 0; ni < 8; ++ni) acc[mi][ni] += av[mi] * wv[ni];
  }
  {
    float4 ba = *(const float4*)(b0 + 8 * tn);
    float4 bb = *(const float4*)(b0 + 8 * tn + 4);
    float bv[8] = {ba.x, ba.y, ba.z, ba.w, bb.x, bb.y, bb.z, bb.w};
#pragma unroll
    for (int mi = 0; mi < 4; ++mi)
#pragma unroll
      for (int ni = 0; ni < 8; ++ni)
        sm.h0t[8 * tn + ni][4 * tm + mi] = fmaxf(acc[mi][ni] + bv[ni], 0.f);
  }
  __syncthreads();

  float acc1[4][8];
#pragma unroll
  for (int mi = 0; mi < 4; ++mi)
#pragma unroll
    for (int ni = 0; ni < 8; ++ni) acc1[mi][ni] = 0.f;

#pragma unroll 4
  for (int k = 0; k < DH; ++k) {
    float4 h4 = *(const float4*)&sm.h0t[k][4 * tm];
    float4 wa = *(const float4*)(w1 + (size_t)k * DH + 8 * tn);
    float4 wb = *(const float4*)(w1 + (size_t)k * DH + 8 * tn + 4);
    float av[4] = {h4.x, h4.y, h4.z, h4.w};
    float wv[8] = {wa.x, wa.y, wa.z, wa.w, wb.x, wb.y, wb.z, wb.w};
#pragma unroll
    for (int mi = 0; mi < 4; ++mi)
#pragma unroll
      for (int ni = 0; ni < 8; ++ni) acc1[mi][ni] += av[mi] * wv[ni];
  }
  {
    float4 ba = *(const float4*)(b1 + 8 * tn);
    float4 bb = *(const float4*)(b1 + 8 * tn + 4);
    float bv[8] = {ba.x, ba.y, ba.z, ba.w, bb.x, bb.y, bb.z, bb.w};
#pragma unroll
    for (int ni = 0; ni < 8; ++ni) {
      float4 o;
      o.x = fmaxf(acc1[0][ni] + bv[ni], 0.f);
      o.y = fmaxf(acc1[1][ni] + bv[ni], 0.f);
      o.z = fmaxf(acc1[2][ni] + bv[ni], 0.f);
      o.w = fmaxf(acc1[3][ni] + bv[ni], 0.f);
      *(float4*)(h1t + (size_t)(8 * tn + ni) * M + m0 + 4 * tm) = o;
    }
  }
}

// ---------------------------------------------------------------------------
// Trans tile (R0-validated 256-thread body): 128x128 output tile at (m0, n0)
// ---------------------------------------------------------------------------
__device__ __forceinline__ void trans_tile(
    const float* __restrict__ h1t, const float* __restrict__ w2,
    const float* __restrict__ b2, float* __restrict__ trans,
    int M, int n0, int m0, SharedGemm& sg, int tid)
{
  const int w  = tid >> 6;
  const int lw = tid & 63;

  auto aload = [&](int t, int buf) {
#pragma unroll
    for (int ii = 0; ii < 2; ++ii) {
      const int i = 2 * w + ii;
      const int kr = 2 * i + (lw >> 5);
      const int c4 = 4 * (lw & 31);
      gl2lds16(h1t + (size_t)(t * TKK + kr) * M + m0 + c4, &sg.As[buf][2 * i][0]);
      gl2lds16(w2 + (size_t)(t * TKK + kr) * DS2 + n0 + c4, &sg.Bs[buf][2 * i][0]);
    }
  };

  aload(0, 0);

  const int mg = tid >> 4;
  const int ng = tid & 15;
  float acc[8][8];
#pragma unroll
  for (int mi = 0; mi < 8; ++mi)
#pragma unroll
    for (int ni = 0; ni < 8; ++ni) acc[mi][ni] = 0.f;

  int buf = 0;
  for (int t = 0; t < DH / TKK; ++t) {
    __syncthreads();
    if (t < DH / TKK - 1) aload(t + 1, buf ^ 1);
#pragma unroll
    for (int k = 0; k < TKK; ++k) {
      float4 a0 = *(const float4*)&sg.As[buf][k][8 * mg];
      float4 a1 = *(const float4*)&sg.As[buf][k][8 * mg + 4];
      float av[8] = {a0.x, a0.y, a0.z, a0.w, a1.x, a1.y, a1.z, a1.w};
      float4 b0v = *(const float4*)&sg.Bs[buf][k][4 * ng];
      float4 b1v = *(const float4*)&sg.Bs[buf][k][64 + 4 * ng];
      float bv[8] = {b0v.x, b0v.y, b0v.z, b0v.w, b1v.x, b1v.y, b1v.z, b1v.w};
#pragma unroll
      for (int mi = 0; mi < 8; ++mi)
#pragma unroll
        for (int ni = 0; ni < 8; ++ni) acc[mi][ni] += av[mi] * bv[ni];
    }
    buf ^= 1;
  }

  float4 bb0 = *(const float4*)(b2 + n0 + 4 * ng);
  float4 bb1 = *(const float4*)(b2 + n0 + 64 + 4 * ng);
  float bv[8] = {bb0.x, bb0.y, bb0.z, bb0.w, bb1.x, bb1.y, bb1.z, bb1.w};
#pragma unroll
  for (int mi = 0; mi < 8; ++mi) {
    float* dst = trans + (size_t)(m0 + 8 * mg + mi) * DS2 + n0;
#pragma unroll
    for (int q = 0; q < 2; ++q) {
      float4 o;
      o.x = acc[mi][4 * q + 0] + bv[4 * q + 0];
      o.y = acc[mi][4 * q + 1] + bv[4 * q + 1];
      o.z = acc[mi][4 * q + 2] + bv[4 * q + 2];
      o.w = acc[mi][4 * q + 3] + bv[4 * q + 3];
      *(float4*)(dst + 64 * q + 4 * ng) = o;
    }
  }
}

// ---------------------------------------------------------------------------
// Standalone MLP kernel (chunk 0 priming)
// ---------------------------------------------------------------------------
__global__ __launch_bounds__(256) void k_mlp01(
    const float* __restrict__ actions, const float* __restrict__ w0,
    const float* __restrict__ b0, const float* __restrict__ w1,
    const float* __restrict__ b1, float* __restrict__ h1t,
    int s_base, int M)
{
  __shared__ SharedMlp sm;
  mlp_tile(actions, w0, b0, w1, b1, h1t, s_base, M, blockIdx.x * 64, sm,
           threadIdx.x);
}

// ---------------------------------------------------------------------------
// Combined pipelined kernel, launch index c = 0..nch, grid 448 x 256 thr:
//  blocks 0..31  : rnn for chunk c-1 (if c>0), reading trans[(c-1)%2]
//  blocks 32..447: trans tiles for chunk c (if c<nch), then mlp for c+1
// 64.1 KB shared union -> 2 blocks/CU: two INDEPENDENT GEMM blocks co-reside
// per CU, so one block's barrier/latency stalls are filled by the other.
// RNN protocol identical to R0 except ring depth 6->4.
// ---------------------------------------------------------------------------
__global__ __launch_bounds__(256, 2) void k_comb(
    const float* __restrict__ actions, const float* __restrict__ w0,
    const float* __restrict__ b0, const float* __restrict__ w1,
    const float* __restrict__ b1, const float* __restrict__ w2,
    const float* __restrict__ b2, const float* __restrict__ init_hidden,
    float* __restrict__ trans0, float* __restrict__ trans1,
    float* __restrict__ h1t0, float* __restrict__ h1t1,
    float* __restrict__ hstate, float* __restrict__ out,
    int c, int SC, int nch)
{
  __shared__ SharedU sh;
  const int tid = threadIdx.x;
  const int M = SC * 32;

  if (blockIdx.x >= 32) {
    // -------------------- GEMM blocks (416) --------------------
    const int bi = blockIdx.x - 32;
    if (c < nch) {
      const float* h1t = (c & 1) ? h1t1 : h1t0;
      float* trans = (c & 1) ? trans1 : trans0;
      const int NJ = (M / 128) * (DS2 / 128);
      for (int j = bi; j < NJ; j += 416) {
        const int mt = j >> 5, nt = j & 31;
        trans_tile(h1t, w2, b2, trans, M, nt * 128, mt * 128, sh.g, tid);
        __syncthreads();
      }
      if (c + 1 < nch) {
        __syncthreads();
        float* h1n = ((c + 1) & 1) ? h1t1 : h1t0;
        for (int j = bi; j < M / 64; j += 416) {
          mlp_tile(actions, w0, b0, w1, b1, h1n, (c + 1) * SC, M, j * 64,
                   sh.m, tid);
          __syncthreads();
        }
      }
    }
    return;
  }

  // -------------------- RNN blocks (chunk c-1), R0 protocol, depth-4 ring --
  if (c == 0) return;
  const int cc = c - 1;
  const float* trans = (cc & 1) ? trans1 : trans0;
  const int s_base = cc * SC;
  const int wv = tid >> 6;            // 0..3
  const int lane = tid & 63;
  const int b = blockIdx.x;

  if (tid < 4) sh.r.flags[tid] = 0;
  if (tid == 4) sh.r.cons = 0;
  __syncthreads();

  const float* base = trans + (size_t)b * DS2;

  if (wv > 0) {
    // producer: steps s ≡ wv-1 (mod 3); ring depth 4 (stride 3 < 4: no
    // circular wait -- gate at s needs cons >= s-3, satisfiable by flags
    // published unconditionally by the other producers' earlier steps)
    const int p = wv - 1;
    int prev = -1;
    for (int s = p; s < SC; s += 3) {
      while (s - __hip_atomic_load(&sh.r.cons, __ATOMIC_RELAXED,
                                   __HIP_MEMORY_SCOPE_WORKGROUP) > 3)
        __builtin_amdgcn_s_sleep(2);
      const int slot = s & 3;
      const float* g = base + (size_t)s * (32 * DS2) + 4 * lane;
      float* l = (float*)&sh.r.ring[slot][0][0];
#pragma unroll
      for (int q = 0; q < 16; ++q)
        gl2lds16(g + q * 256, l + q * 256);
      if (prev >= 0) {
        asm volatile("s_waitcnt vmcnt(16)" ::: "memory");
        __hip_atomic_store(&sh.r.flags[prev & 3], prev + 1, __ATOMIC_RELAXED,
                           __HIP_MEMORY_SCOPE_WORKGROUP);
      }
      prev = s;
    }
    if (prev >= 0) {
      asm volatile("s_waitcnt vmcnt(0)" ::: "memory");
      __hip_atomic_store(&sh.r.flags[prev & 3], prev + 1, __ATOMIC_RELAXED,
                         __HIP_MEMORY_SCOPE_WORKGROUP);
    }
  } else {
    // consumer: serial recurrence
    const int d = lane >> 4;
    const int cq = lane & 15;
    const bool d1 = (d & 1), d2 = (d & 2);
    const int pb = lane & 48;

    float4 hq;
    if (cc == 0) {
      hq = *(const float4*)(init_hidden + 4 * cq);
      float ss0 = row_sum16(hq.x * hq.x + hq.y * hq.y + hq.z * hq.z + hq.w * hq.w);
      float iv0 = 1.0f / fmaxf(sqrtf(ss0), 1e-12f);
      hq.x *= iv0; hq.y *= iv0; hq.z *= iv0; hq.w *= iv0;
    } else {
      hq = *(const float4*)(hstate + b * DS + 4 * cq);
    }
    float inv_prev = 1.0f;

    float* outp = out + ((size_t)b * S_ + s_base) * DS + 4 * cq;
    int fpre = -1;
    for (int s = 0; s < SC; ++s) {
      const int slot = s & 3;
      if (fpre < s + 1) {
        while (__hip_atomic_load(&sh.r.flags[slot], __ATOMIC_ACQUIRE,
                                 __HIP_MEMORY_SCOPE_WORKGROUP) < s + 1)
          __builtin_amdgcn_s_sleep(0);
      }
      fpre = __hip_atomic_load(&sh.r.flags[(s + 1) & 3], __ATOMIC_ACQUIRE,
                               __HIP_MEMORY_SCOPE_WORKGROUP);

      float hsel = d2 ? (d1 ? hq.w : hq.z) : (d1 ? hq.y : hq.x);
      float ax = 0.f, ay = 0.f, az = 0.f, aw = 0.f;
#pragma unroll
      for (int q = 0; q < 16; ++q) {
        float4 t4 = sh.r.ring[slot][q][lane];
        float hb = __shfl(hsel, pb + q, 64);
        ax += hb * t4.x; ay += hb * t4.y;
        az += hb * t4.z; aw += hb * t4.w;
      }
      __hip_atomic_store(&sh.r.cons, s + 1, __ATOMIC_RELAXED,
                         __HIP_MEMORY_SCOPE_WORKGROUP);

      ax += __shfl_xor(ax, 16, 64); ax += __shfl_xor(ax, 32, 64);
      ay += __shfl_xor(ay, 16, 64); ay += __shfl_xor(ay, 32, 64);
      az += __shfl_xor(az, 16, 64); az += __shfl_xor(az, 32, 64);
      aw += __shfl_xor(aw, 16, 64); aw += __shfl_xor(aw, 32, 64);
      hq.x = fmaxf(ax * inv_prev, 0.f);
      hq.y = fmaxf(ay * inv_prev, 0.f);
      hq.z = fmaxf(az * inv_prev, 0.f);
      hq.w = fmaxf(aw * inv_prev, 0.f);
      float ss = row_sum16(hq.x * hq.x + hq.y * hq.y + hq.z * hq.z + hq.w * hq.w);
      float inv = 1.0f / fmaxf(sqrtf(ss), 1e-12f);
      if (d == 0) {
        float4 o;
        o.x = hq.x * inv; o.y = hq.y * inv; o.z = hq.z * inv; o.w = hq.w * inv;
        *(float4*)(outp + (size_t)s * DS) = o;
      }
      inv_prev = inv;
    }
    if (d == 0) {
      float4 o;   // carry NORMALIZED state across chunks
      o.x = hq.x * inv_prev; o.y = hq.y * inv_prev;
      o.z = hq.z * inv_prev; o.w = hq.w * inv_prev;
      *(float4*)(hstate + b * DS + 4 * cq) = o;
    }
  }
}

// ---------------------------------------------------------------------------
extern "C" void kernel_launch(void* const* d_in, const int* in_sizes, int n_in,
                              void* d_out, int out_size, void* d_ws, size_t ws_size,
                              hipStream_t stream) {
  const float* actions     = (const float*)d_in[0];
  const float* w0          = (const float*)d_in[1];
  const float* b0          = (const float*)d_in[2];
  const float* w1          = (const float*)d_in[3];
  const float* b1          = (const float*)d_in[4];
  const float* w2          = (const float*)d_in[5];
  const float* b2          = (const float*)d_in[6];
  const float* init_hidden = (const float*)d_in[7];
  float* out = (float*)d_out;

  // largest chunk whose DOUBLE-buffered workspace fits
  int SC = 2048;
  while (SC > 4) {
    size_t need = 2 * ((size_t)SC * 32 * DS2 * 4 + (size_t)SC * 32 * DH * 4)
                + (size_t)B_ * DS * 4;
    if (need <= ws_size) break;
    SC >>= 1;
  }
  float* trans0 = (float*)d_ws;
  float* trans1 = trans0 + (size_t)SC * 32 * DS2;
  float* h1t0   = trans1 + (size_t)SC * 32 * DS2;
  float* h1t1   = h1t0 + (size_t)SC * 32 * DH;
  float* hstate = h1t1 + (size_t)SC * 32 * DH;

  const int M = SC * 32;
  const int nch = S_ / SC;

  // prime: mlp for chunk 0 -> h1t0
  hipLaunchKernelGGL(k_mlp01, dim3(M / 64), dim3(256), 0, stream,
                     actions, w0, b0, w1, b1, h1t0, 0, M);
  // pipelined combined launches
  for (int c = 0; c <= nch; ++c) {
    hipLaunchKernelGGL(k_comb, dim3(448), dim3(256), 0, stream,
                       actions, w0, b0, w1, b1, w2, b2, init_hidden,
                       trans0, trans1, h1t0, h1t1, hstate, out, c, SC, nch);
  }
}

// Round 8
// 1726.787 us; speedup vs baseline: 1.4550x; 1.4550x over previous
//
#include <hip/hip_runtime.h>

// Problem constants
#define B_ 32
#define S_ 2048
#define DA 32
#define DH 128
#define DS 64
#define DS2 4096
#define TKK 16

template <int CTRL>
__device__ __forceinline__ float dpp_add(float x) {
  int t = __builtin_amdgcn_update_dpp(0, __float_as_int(x), CTRL, 0xF, 0xF, true);
  return x + __int_as_float(t);
}
// sum over the 16 lanes of each row, result uniform within the row
__device__ __forceinline__ float row_sum16(float x) {
  x = dpp_add<0xB1>(x);
  x = dpp_add<0x4E>(x);
  x = dpp_add<0x141>(x);
  x = dpp_add<0x140>(x);
  return x;
}

// async global->LDS DMA, 16 B per lane (dest = wave-uniform base + lane*16)
__device__ __forceinline__ void gl2lds16(const float* g, float* l) {
  __builtin_amdgcn_global_load_lds(
      (const __attribute__((address_space(1))) void*)g,
      (__attribute__((address_space(3))) void*)l, 16, 0, 0);
}

// ---------------------------------------------------------------------------
// Shared union = max(32 KB gemm, 56 KB mlp) = 57344 B <= 64 KB.
// R7 evidence: workgroups with >64 KB LDS never co-reside (occupancy stayed
// at the 1-block value); <=64 KB allows the intended 2 blocks/CU so two
// INDEPENDENT GEMM blocks overlap barrier/latency stalls (m114).
// The RNN LDS ring is deleted: the consumer reads trans directly from
// global (L3-resident, written by the previous dispatch) with a 2-deep
// register ping-pong prefetch. No producers, no flags, no deadlock class.
// ---------------------------------------------------------------------------
struct SharedGemm {
  float As[2][TKK][128];    // 16 KB
  float Bs[2][TKK][128];    // 16 KB
};
struct SharedMlp {
  float a_t[DA][64];        // 8 KB
  float w0_l[DA][DH];       // 16 KB
  float h0t[DH][64];        // 32 KB
};
union SharedU {
  SharedGemm g;
  SharedMlp m;
};

// ---------------------------------------------------------------------------
// MLP tile (R0-validated 256-thread body): 64 tokens -> h1t[f][tok]
// ---------------------------------------------------------------------------
__device__ __forceinline__ void mlp_tile(
    const float* __restrict__ actions, const float* __restrict__ w0,
    const float* __restrict__ b0, const float* __restrict__ w1,
    const float* __restrict__ b1, float* __restrict__ h1t,
    int s_base, int M, int m0, SharedMlp& sm, int tid)
{
#pragma unroll
  for (int q = 0; q < 2; ++q) {
    int g = tid + 256 * q;
    int tok = g >> 3, kq = g & 7;
    int tl = m0 + tok;
    int b = tl & 31, s = s_base + (tl >> 5);
    float4 v = *(const float4*)(actions + ((size_t)b * S_ + s) * DA + 4 * kq);
    sm.a_t[4 * kq + 0][tok] = v.x; sm.a_t[4 * kq + 1][tok] = v.y;
    sm.a_t[4 * kq + 2][tok] = v.z; sm.a_t[4 * kq + 3][tok] = v.w;
  }
#pragma unroll
  for (int q = 0; q < 4; ++q) {
    int g = tid + 256 * q;
    ((float4*)&sm.w0_l[0][0])[g] = ((const float4*)w0)[g];
  }
  __syncthreads();

  const int tm = tid & 15;
  const int tn = tid >> 4;

  float acc[4][8];
#pragma unroll
  for (int mi = 0; mi < 4; ++mi)
#pragma unroll
    for (int ni = 0; ni < 8; ++ni) acc[mi][ni] = 0.f;

#pragma unroll 4
  for (int k = 0; k < DA; ++k) {
    float4 a4 = *(const float4*)&sm.a_t[k][4 * tm];
    float4 wa = *(const float4*)&sm.w0_l[k][8 * tn];
    float4 wb = *(const float4*)&sm.w0_l[k][8 * tn + 4];
    float av[4] = {a4.x, a4.y, a4.z, a4.w};
    float wv[8] = {wa.x, wa.y, wa.z, wa.w, wb.x, wb.y, wb.z, wb.w};
#pragma unroll
    for (int mi = 0; mi < 4; ++mi)
#pragma unroll
      for (int ni = 0; ni < 8; ++ni) acc[mi][ni] += av[mi] * wv[ni];
  }
  {
    float4 ba = *(const float4*)(b0 + 8 * tn);
    float4 bb = *(const float4*)(b0 + 8 * tn + 4);
    float bv[8] = {ba.x, ba.y, ba.z, ba.w, bb.x, bb.y, bb.z, bb.w};
#pragma unroll
    for (int mi = 0; mi < 4; ++mi)
#pragma unroll
      for (int ni = 0; ni < 8; ++ni)
        sm.h0t[8 * tn + ni][4 * tm + mi] = fmaxf(acc[mi][ni] + bv[ni], 0.f);
  }
  __syncthreads();

  float acc1[4][8];
#pragma unroll
  for (int mi = 0; mi < 4; ++mi)
#pragma unroll
    for (int ni = 0; ni < 8; ++ni) acc1[mi][ni] = 0.f;

#pragma unroll 4
  for (int k = 0; k < DH; ++k) {
    float4 h4 = *(const float4*)&sm.h0t[k][4 * tm];
    float4 wa = *(const float4*)(w1 + (size_t)k * DH + 8 * tn);
    float4 wb = *(const float4*)(w1 + (size_t)k * DH + 8 * tn + 4);
    float av[4] = {h4.x, h4.y, h4.z, h4.w};
    float wv[8] = {wa.x, wa.y, wa.z, wa.w, wb.x, wb.y, wb.z, wb.w};
#pragma unroll
    for (int mi = 0; mi < 4; ++mi)
#pragma unroll
      for (int ni = 0; ni < 8; ++ni) acc1[mi][ni] += av[mi] * wv[ni];
  }
  {
    float4 ba = *(const float4*)(b1 + 8 * tn);
    float4 bb = *(const float4*)(b1 + 8 * tn + 4);
    float bv[8] = {ba.x, ba.y, ba.z, ba.w, bb.x, bb.y, bb.z, bb.w};
#pragma unroll
    for (int ni = 0; ni < 8; ++ni) {
      float4 o;
      o.x = fmaxf(acc1[0][ni] + bv[ni], 0.f);
      o.y = fmaxf(acc1[1][ni] + bv[ni], 0.f);
      o.z = fmaxf(acc1[2][ni] + bv[ni], 0.f);
      o.w = fmaxf(acc1[3][ni] + bv[ni], 0.f);
      *(float4*)(h1t + (size_t)(8 * tn + ni) * M + m0 + 4 * tm) = o;
    }
  }
}

// ---------------------------------------------------------------------------
// Trans tile (R0-validated 256-thread body): 128x128 output tile at (m0, n0)
// ---------------------------------------------------------------------------
__device__ __forceinline__ void trans_tile(
    const float* __restrict__ h1t, const float* __restrict__ w2,
    const float* __restrict__ b2, float* __restrict__ trans,
    int M, int n0, int m0, SharedGemm& sg, int tid)
{
  const int w  = tid >> 6;
  const int lw = tid & 63;

  auto aload = [&](int t, int buf) {
#pragma unroll
    for (int ii = 0; ii < 2; ++ii) {
      const int i = 2 * w + ii;
      const int kr = 2 * i + (lw >> 5);
      const int c4 = 4 * (lw & 31);
      gl2lds16(h1t + (size_t)(t * TKK + kr) * M + m0 + c4, &sg.As[buf][2 * i][0]);
      gl2lds16(w2 + (size_t)(t * TKK + kr) * DS2 + n0 + c4, &sg.Bs[buf][2 * i][0]);
    }
  };

  aload(0, 0);

  const int mg = tid >> 4;
  const int ng = tid & 15;
  float acc[8][8];
#pragma unroll
  for (int mi = 0; mi < 8; ++mi)
#pragma unroll
    for (int ni = 0; ni < 8; ++ni) acc[mi][ni] = 0.f;

  int buf = 0;
  for (int t = 0; t < DH / TKK; ++t) {
    __syncthreads();
    if (t < DH / TKK - 1) aload(t + 1, buf ^ 1);
#pragma unroll
    for (int k = 0; k < TKK; ++k) {
      float4 a0 = *(const float4*)&sg.As[buf][k][8 * mg];
      float4 a1 = *(const float4*)&sg.As[buf][k][8 * mg + 4];
      float av[8] = {a0.x, a0.y, a0.z, a0.w, a1.x, a1.y, a1.z, a1.w};
      float4 b0v = *(const float4*)&sg.Bs[buf][k][4 * ng];
      float4 b1v = *(const float4*)&sg.Bs[buf][k][64 + 4 * ng];
      float bv[8] = {b0v.x, b0v.y, b0v.z, b0v.w, b1v.x, b1v.y, b1v.z, b1v.w};
#pragma unroll
      for (int mi = 0; mi < 8; ++mi)
#pragma unroll
        for (int ni = 0; ni < 8; ++ni) acc[mi][ni] += av[mi] * bv[ni];
    }
    buf ^= 1;
  }

  float4 bb0 = *(const float4*)(b2 + n0 + 4 * ng);
  float4 bb1 = *(const float4*)(b2 + n0 + 64 + 4 * ng);
  float bv[8] = {bb0.x, bb0.y, bb0.z, bb0.w, bb1.x, bb1.y, bb1.z, bb1.w};
#pragma unroll
  for (int mi = 0; mi < 8; ++mi) {
    float* dst = trans + (size_t)(m0 + 8 * mg + mi) * DS2 + n0;
#pragma unroll
    for (int q = 0; q < 2; ++q) {
      float4 o;
      o.x = acc[mi][4 * q + 0] + bv[4 * q + 0];
      o.y = acc[mi][4 * q + 1] + bv[4 * q + 1];
      o.z = acc[mi][4 * q + 2] + bv[4 * q + 2];
      o.w = acc[mi][4 * q + 3] + bv[4 * q + 3];
      *(float4*)(dst + 64 * q + 4 * ng) = o;
    }
  }
}

// ---------------------------------------------------------------------------
// Standalone MLP kernel (chunk 0 priming)
// ---------------------------------------------------------------------------
__global__ __launch_bounds__(256) void k_mlp01(
    const float* __restrict__ actions, const float* __restrict__ w0,
    const float* __restrict__ b0, const float* __restrict__ w1,
    const float* __restrict__ b1, float* __restrict__ h1t,
    int s_base, int M)
{
  __shared__ SharedMlp sm;
  mlp_tile(actions, w0, b0, w1, b1, h1t, s_base, M, blockIdx.x * 64, sm,
           threadIdx.x);
}

// ---------------------------------------------------------------------------
// Combined pipelined kernel, launch index c = 0..nch, grid 480 x 256 thr:
//  blocks 0..31  : rnn for chunk c-1 (if c>0) -- ONE consumer wave reading
//                  trans directly from global (L3-resident) with 2-deep
//                  register ping-pong prefetch; waves 1..3 idle.
//  blocks 32..479: trans tiles for chunk c (if c<nch), then mlp for c+1.
// 56 KB shared union -> 2 blocks/CU: two independent GEMM blocks per CU
// overlap each other's barrier drains and LDS-latency stalls.
// ---------------------------------------------------------------------------
__global__ __launch_bounds__(256, 2) void k_comb(
    const float* __restrict__ actions, const float* __restrict__ w0,
    const float* __restrict__ b0, const float* __restrict__ w1,
    const float* __restrict__ b1, const float* __restrict__ w2,
    const float* __restrict__ b2, const float* __restrict__ init_hidden,
    float* __restrict__ trans0, float* __restrict__ trans1,
    float* __restrict__ h1t0, float* __restrict__ h1t1,
    float* __restrict__ hstate, float* __restrict__ out,
    int c, int SC, int nch)
{
  __shared__ SharedU sh;
  const int tid = threadIdx.x;
  const int M = SC * 32;

  if (blockIdx.x >= 32) {
    // -------------------- GEMM blocks (448) --------------------
    const int bi = blockIdx.x - 32;
    if (c < nch) {
      const float* h1t = (c & 1) ? h1t1 : h1t0;
      float* trans = (c & 1) ? trans1 : trans0;
      const int NJ = (M / 128) * (DS2 / 128);
      for (int j = bi; j < NJ; j += 448) {
        const int mt = j >> 5, nt = j & 31;
        trans_tile(h1t, w2, b2, trans, M, nt * 128, mt * 128, sh.g, tid);
        __syncthreads();
      }
      if (c + 1 < nch) {
        __syncthreads();
        float* h1n = ((c + 1) & 1) ? h1t1 : h1t0;
        for (int j = bi; j < M / 64; j += 448) {
          mlp_tile(actions, w0, b0, w1, b1, h1n, (c + 1) * SC, M, j * 64,
                   sh.m, tid);
          __syncthreads();
        }
      }
    }
    return;
  }

  // ---------------- RNN blocks (chunk c-1), direct-global consumer --------
  if (c == 0) return;
  if (tid >= 64) return;              // single consumer wave per block
  const int cc = c - 1;
  const float* trans = (cc & 1) ? trans1 : trans0;
  const int s_base = cc * SC;
  const int lane = tid;
  const int b = blockIdx.x;

  const int d = lane >> 4;
  const int cq = lane & 15;
  const bool d1 = (d & 1), d2 = (d & 2);
  const int pb = lane & 48;

  float4 hq;
  if (cc == 0) {
    hq = *(const float4*)(init_hidden + 4 * cq);
    float ss0 = row_sum16(hq.x * hq.x + hq.y * hq.y + hq.z * hq.z + hq.w * hq.w);
    float iv0 = 1.0f / fmaxf(sqrtf(ss0), 1e-12f);
    hq.x *= iv0; hq.y *= iv0; hq.z *= iv0; hq.w *= iv0;
  } else {
    hq = *(const float4*)(hstate + b * DS + 4 * cq);
  }
  float inv_prev = 1.0f;

  float* outp = out + ((size_t)b * S_ + s_base) * DS + 4 * cq;
  const float* g0 = trans + (size_t)b * DS2 + 4 * lane;
  const size_t sstride = (size_t)32 * DS2;

  // one RNN step from a register-resident T-slice (identical math to R0)
  auto step_fn = [&](const float4 (&T)[16], int s) {
    float hsel = d2 ? (d1 ? hq.w : hq.z) : (d1 ? hq.y : hq.x);
    float ax = 0.f, ay = 0.f, az = 0.f, aw = 0.f;
#pragma unroll
    for (int q = 0; q < 16; ++q) {
      float hb = __shfl(hsel, pb + q, 64);
      ax += hb * T[q].x; ay += hb * T[q].y;
      az += hb * T[q].z; aw += hb * T[q].w;
    }
    ax += __shfl_xor(ax, 16, 64); ax += __shfl_xor(ax, 32, 64);
    ay += __shfl_xor(ay, 16, 64); ay += __shfl_xor(ay, 32, 64);
    az += __shfl_xor(az, 16, 64); az += __shfl_xor(az, 32, 64);
    aw += __shfl_xor(aw, 16, 64); aw += __shfl_xor(aw, 32, 64);
    hq.x = fmaxf(ax * inv_prev, 0.f);
    hq.y = fmaxf(ay * inv_prev, 0.f);
    hq.z = fmaxf(az * inv_prev, 0.f);
    hq.w = fmaxf(aw * inv_prev, 0.f);
    float ss = row_sum16(hq.x * hq.x + hq.y * hq.y + hq.z * hq.z + hq.w * hq.w);
    float inv = 1.0f / fmaxf(sqrtf(ss), 1e-12f);
    if (d == 0) {
      float4 o;
      o.x = hq.x * inv; o.y = hq.y * inv; o.z = hq.z * inv; o.w = hq.w * inv;
      *(float4*)(outp + (size_t)s * DS) = o;
    }
    inv_prev = inv;
  };

  float4 A[16], Bv[16];
#pragma unroll
  for (int q = 0; q < 16; ++q) A[q] = *(const float4*)(g0 + q * 256);

  for (int s = 0; s < SC; s += 2) {     // SC is even (power of two >= 8)
    const float* g1 = g0 + (size_t)(s + 1) * sstride;
#pragma unroll
    for (int q = 0; q < 16; ++q) Bv[q] = *(const float4*)(g1 + q * 256);
    step_fn(A, s);
    if (s + 2 < SC) {
      const float* g2 = g0 + (size_t)(s + 2) * sstride;
#pragma unroll
      for (int q = 0; q < 16; ++q) A[q] = *(const float4*)(g2 + q * 256);
    }
    step_fn(Bv, s + 1);
  }

  if (d == 0) {
    float4 o;   // carry NORMALIZED state across chunks
    o.x = hq.x * inv_prev; o.y = hq.y * inv_prev;
    o.z = hq.z * inv_prev; o.w = hq.w * inv_prev;
    *(float4*)(hstate + b * DS + 4 * cq) = o;
  }
}

// ---------------------------------------------------------------------------
extern "C" void kernel_launch(void* const* d_in, const int* in_sizes, int n_in,
                              void* d_out, int out_size, void* d_ws, size_t ws_size,
                              hipStream_t stream) {
  const float* actions     = (const float*)d_in[0];
  const float* w0          = (const float*)d_in[1];
  const float* b0          = (const float*)d_in[2];
  const float* w1          = (const float*)d_in[3];
  const float* b1          = (const float*)d_in[4];
  const float* w2          = (const float*)d_in[5];
  const float* b2          = (const float*)d_in[6];
  const float* init_hidden = (const float*)d_in[7];
  float* out = (float*)d_out;

  // largest chunk whose DOUBLE-buffered workspace fits
  int SC = 2048;
  while (SC > 4) {
    size_t need = 2 * ((size_t)SC * 32 * DS2 * 4 + (size_t)SC * 32 * DH * 4)
                + (size_t)B_ * DS * 4;
    if (need <= ws_size) break;
    SC >>= 1;
  }
  float* trans0 = (float*)d_ws;
  float* trans1 = trans0 + (size_t)SC * 32 * DS2;
  float* h1t0   = trans1 + (size_t)SC * 32 * DS2;
  float* h1t1   = h1t0 + (size_t)SC * 32 * DH;
  float* hstate = h1t1 + (size_t)SC * 32 * DH;

  const int M = SC * 32;
  const int nch = S_ / SC;

  // prime: mlp for chunk 0 -> h1t0
  hipLaunchKernelGGL(k_mlp01, dim3(M / 64), dim3(256), 0, stream,
                     actions, w0, b0, w1, b1, h1t0, 0, M);
  // pipelined combined launches
  for (int c = 0; c <= nch; ++c) {
    hipLaunchKernelGGL(k_comb, dim3(480), dim3(256), 0, stream,
                       actions, w0, b0, w1, b1, w2, b2, init_hidden,
                       trans0, trans1, h1t0, h1t1, hstate, out, c, SC, nch);
  }
}

// Round 10
// 1586.141 us; speedup vs baseline: 1.5840x; 1.0887x over previous
//
#include <hip/hip_runtime.h>

// Problem constants
#define B_ 32
#define S_ 2048
#define DA 32
#define DH 128
#define DS 64
#define DS2 4096

typedef _Float16 half8 __attribute__((ext_vector_type(8)));
typedef float f32x4 __attribute__((ext_vector_type(4)));

template <int CTRL>
__device__ __forceinline__ float dpp_add(float x) {
  int t = __builtin_amdgcn_update_dpp(0, __float_as_int(x), CTRL, 0xF, 0xF, true);
  return x + __int_as_float(t);
}
__device__ __forceinline__ float row_sum16(float x) {
  x = dpp_add<0xB1>(x);
  x = dpp_add<0x4E>(x);
  x = dpp_add<0x141>(x);
  x = dpp_add<0x140>(x);
  return x;
}

// async global->LDS DMA, 16 B per lane (dest = wave-uniform base + lane*16)
__device__ __forceinline__ void gl2lds16(const void* g, void* l) {
  __builtin_amdgcn_global_load_lds(
      (const __attribute__((address_space(1))) void*)g,
      (__attribute__((address_space(3))) void*)l, 16, 0, 0);
}

// ---------------------------------------------------------------------------
// R0-R8 evidence: the fp32 GEMM is capped by per-CU instruction throughput
// (~3x the FMA issue floor), invariant to occupancy/operands/barriers/
// pipelining/co-residency. Fix: MFMA (16x16x32 f16) with fp16 2-way operand
// splitting, ALL FOUR product terms kept (hh, cross*2^-11, ll*2^-22) ->
// representation error ~2^-22 = fp32-class, so the recurrence's error
// amplification stays at current levels.
// LDS: Ah/Al (per-tile A, [m][k^swz]) + Bh/Bl (per-n-strip pinned w2 split,
// [n][k^swz]) = 128 KB. Swizzle is pre-applied in the GLOBAL arrays so
// global_load_lds stages linearly and ds_read_b128 reads conflict-free
// (both-sides-or-neither rule).
// ---------------------------------------------------------------------------
struct SharedGemm {
  _Float16 Ah[128 * 128];   // 32 KB  [m*128 + (k ^ ((m&7)<<3))]
  _Float16 Al[128 * 128];
  _Float16 Bh[128 * 128];   // 32 KB  [nloc*128 + (k ^ ((n&7)<<3))]
  _Float16 Bl[128 * 128];
};
struct SharedMlp {
  float a_t[DA][64];        // 8 KB
  float w0_l[DA][DH];       // 16 KB
  float h0t[DH][64];        // 32 KB
};
union SharedU {
  SharedGemm g;
  SharedMlp m;
};

// ---------------------------------------------------------------------------
// w2 split precompute (once): w2 [k][n] fp32 -> w2h/w2l [n][k^swz] fp16,
// lo scaled by 2^11 so it stays in fp16 normal range.
// ---------------------------------------------------------------------------
__global__ __launch_bounds__(256) void k_split(
    const float* __restrict__ w2, _Float16* __restrict__ w2h,
    _Float16* __restrict__ w2l)
{
  for (int e = blockIdx.x * 256 + threadIdx.x; e < DH * DS2;
       e += gridDim.x * 256) {
    int n = e >> 7, k = e & 127;
    float v = w2[(size_t)k * DS2 + n];
    _Float16 hi = (_Float16)v;
    _Float16 lo = (_Float16)((v - (float)hi) * 2048.0f);
    int kk = k ^ ((n & 7) << 3);
    w2h[(size_t)n * DH + kk] = hi;
    w2l[(size_t)n * DH + kk] = lo;
  }
}

// ---------------------------------------------------------------------------
// MLP tile (R0-validated 256-thread compute): 64 tokens; epilogue emits the
// fp16 hi/lo split of h1 in [m][k^swz] layout (k = feature).
// ---------------------------------------------------------------------------
__device__ __forceinline__ void mlp_tile(
    const float* __restrict__ actions, const float* __restrict__ w0,
    const float* __restrict__ b0, const float* __restrict__ w1,
    const float* __restrict__ b1, _Float16* __restrict__ h1h,
    _Float16* __restrict__ h1l, int s_base, int m0, SharedMlp& sm, int tid)
{
#pragma unroll
  for (int q = 0; q < 2; ++q) {
    int g = tid + 256 * q;
    int tok = g >> 3, kq = g & 7;
    int tl = m0 + tok;
    int b = tl & 31, s = s_base + (tl >> 5);
    float4 v = *(const float4*)(actions + ((size_t)b * S_ + s) * DA + 4 * kq);
    sm.a_t[4 * kq + 0][tok] = v.x; sm.a_t[4 * kq + 1][tok] = v.y;
    sm.a_t[4 * kq + 2][tok] = v.z; sm.a_t[4 * kq + 3][tok] = v.w;
  }
#pragma unroll
  for (int q = 0; q < 4; ++q) {
    int g = tid + 256 * q;
    ((float4*)&sm.w0_l[0][0])[g] = ((const float4*)w0)[g];
  }
  __syncthreads();

  const int tm = tid & 15;
  const int tn = tid >> 4;

  float acc[4][8];
#pragma unroll
  for (int mi = 0; mi < 4; ++mi)
#pragma unroll
    for (int ni = 0; ni < 8; ++ni) acc[mi][ni] = 0.f;

#pragma unroll 4
  for (int k = 0; k < DA; ++k) {
    float4 a4 = *(const float4*)&sm.a_t[k][4 * tm];
    float4 wa = *(const float4*)&sm.w0_l[k][8 * tn];
    float4 wb = *(const float4*)&sm.w0_l[k][8 * tn + 4];
    float av[4] = {a4.x, a4.y, a4.z, a4.w};
    float wv[8] = {wa.x, wa.y, wa.z, wa.w, wb.x, wb.y, wb.z, wb.w};
#pragma unroll
    for (int mi = 0; mi < 4; ++mi)
#pragma unroll
      for (int ni = 0; ni < 8; ++ni) acc[mi][ni] += av[mi] * wv[ni];
  }
  {
    float4 ba = *(const float4*)(b0 + 8 * tn);
    float4 bb = *(const float4*)(b0 + 8 * tn + 4);
    float bv[8] = {ba.x, ba.y, ba.z, ba.w, bb.x, bb.y, bb.z, bb.w};
#pragma unroll
    for (int mi = 0; mi < 4; ++mi)
#pragma unroll
      for (int ni = 0; ni < 8; ++ni)
        sm.h0t[8 * tn + ni][4 * tm + mi] = fmaxf(acc[mi][ni] + bv[ni], 0.f);
  }
  __syncthreads();

  float acc1[4][8];
#pragma unroll
  for (int mi = 0; mi < 4; ++mi)
#pragma unroll
    for (int ni = 0; ni < 8; ++ni) acc1[mi][ni] = 0.f;

#pragma unroll 4
  for (int k = 0; k < DH; ++k) {
    float4 h4 = *(const float4*)&sm.h0t[k][4 * tm];
    float4 wa = *(const float4*)(w1 + (size_t)k * DH + 8 * tn);
    float4 wb = *(const float4*)(w1 + (size_t)k * DH + 8 * tn + 4);
    float av[4] = {h4.x, h4.y, h4.z, h4.w};
    float wv[8] = {wa.x, wa.y, wa.z, wa.w, wb.x, wb.y, wb.z, wb.w};
#pragma unroll
    for (int mi = 0; mi < 4; ++mi)
#pragma unroll
      for (int ni = 0; ni < 8; ++ni) acc1[mi][ni] += av[mi] * wv[ni];
  }
  {
    float4 ba = *(const float4*)(b1 + 8 * tn);
    float4 bb = *(const float4*)(b1 + 8 * tn + 4);
    float bv[8] = {ba.x, ba.y, ba.z, ba.w, bb.x, bb.y, bb.z, bb.w};
#pragma unroll
    for (int mi = 0; mi < 4; ++mi) {
      const int m = m0 + 4 * tm + mi;
      half8 hv, lv;
#pragma unroll
      for (int ni = 0; ni < 8; ++ni) {
        float h = fmaxf(acc1[mi][ni] + bv[ni], 0.f);
        _Float16 hi = (_Float16)h;
        hv[ni] = hi;
        lv[ni] = (_Float16)((h - (float)hi) * 2048.0f);
      }
      const int off = m * DH + ((8 * tn) ^ ((m & 7) << 3));
      *(half8*)(h1h + off) = hv;
      *(half8*)(h1l + off) = lv;
    }
  }
}

// ---------------------------------------------------------------------------
// MFMA trans GEMM: block owns n-strip (strip = x/7); Bh/Bl pinned once;
// per m-tile: stage Ah/Al (64 KB, linear DMA) -> MFMA -> store.
// Waves: 2x2 quadrants of the 128x128 tile; per wave 4x4 fragments of
// 16x16, K=128 as 4 chunks of 32. A layout: row = lane&15,
// k = (lane>>4)*8 + j; B: col = lane&15, same k (CDNA standard).
// C/D: col = lane&15, row = (lane>>4)*4 + reg (guide m89/m91 verified).
// ---------------------------------------------------------------------------
__device__ __forceinline__ void trans_loop(
    const _Float16* __restrict__ h1h, const _Float16* __restrict__ h1l,
    const _Float16* __restrict__ w2h, const _Float16* __restrict__ w2l,
    const float* __restrict__ b2, float* __restrict__ trans,
    int MT, int x, SharedGemm& sg, int tid)
{
  const int w  = tid >> 6;
  const int lw = tid & 63;
  const int strip = x / 7;            // 0..31
  const int idx   = x % 7;
  const int n0 = strip * 128;

  // per-wave linear 8 KB staging helper (32 KB array / 4 waves)
  auto stage32k = [&](const _Float16* src, _Float16* dst) {
    const _Float16* s = src + w * 4096 + lw * 8;
    _Float16* d = dst + w * 4096;
#pragma unroll
    for (int i = 0; i < 8; ++i)
      gl2lds16(s + i * 512, d + i * 512);
  };

  // pin B strip (w2 splits are [n][k^swz], contiguous per strip)
  stage32k(w2h + (size_t)n0 * DH, sg.Bh);
  stage32k(w2l + (size_t)n0 * DH, sg.Bl);

  const int fr = lw & 15;             // frag row/col index
  const int kg = lw >> 4;             // 0..3 k-group
  const int wr = w >> 1, wc = w & 1;  // wave quadrant

  float b2v[4];
#pragma unroll
  for (int fn = 0; fn < 4; ++fn)
    b2v[fn] = b2[n0 + wc * 64 + fn * 16 + fr];

  const f32x4 fz = {0.f, 0.f, 0.f, 0.f};

  for (int mt = idx; mt < MT; mt += 7) {
    const int m0 = mt * 128;
    stage32k(h1h + (size_t)m0 * DH, sg.Ah);
    stage32k(h1l + (size_t)m0 * DH, sg.Al);
    asm volatile("s_waitcnt vmcnt(0)" ::: "memory");
    __syncthreads();

    f32x4 ahh[4][4], axx[4][4], all_[4][4];
#pragma unroll
    for (int fm = 0; fm < 4; ++fm)
#pragma unroll
      for (int fn = 0; fn < 4; ++fn) {
        ahh[fm][fn] = fz;
        axx[fm][fn] = fz;
        all_[fm][fn] = fz;
      }

#pragma unroll
    for (int kc = 0; kc < 4; ++kc) {
      const int k0 = kc * 32 + kg * 8;
      half8 bh[4], bl[4];
#pragma unroll
      for (int fn = 0; fn < 4; ++fn) {
        const int n = wc * 64 + fn * 16 + fr;
        const int off = n * DH + (k0 ^ ((n & 7) << 3));
        bh[fn] = *(const half8*)&sg.Bh[off];
        bl[fn] = *(const half8*)&sg.Bl[off];
      }
#pragma unroll
      for (int fm = 0; fm < 4; ++fm) {
        const int m = wr * 64 + fm * 16 + fr;
        const int off = m * DH + (k0 ^ ((m & 7) << 3));
        half8 ah = *(const half8*)&sg.Ah[off];
        half8 al = *(const half8*)&sg.Al[off];
#pragma unroll
        for (int fn = 0; fn < 4; ++fn) {
          ahh[fm][fn] = __builtin_amdgcn_mfma_f32_16x16x32_f16(
              ah, bh[fn], ahh[fm][fn], 0, 0, 0);
          axx[fm][fn] = __builtin_amdgcn_mfma_f32_16x16x32_f16(
              ah, bl[fn], axx[fm][fn], 0, 0, 0);
          axx[fm][fn] = __builtin_amdgcn_mfma_f32_16x16x32_f16(
              al, bh[fn], axx[fm][fn], 0, 0, 0);
          all_[fm][fn] = __builtin_amdgcn_mfma_f32_16x16x32_f16(
              al, bl[fn], all_[fm][fn], 0, 0, 0);
        }
      }
    }
    __syncthreads();   // all LDS reads done before next tile's staging

    // epilogue: C/D layout col = lane&15, row = (lane>>4)*4 + reg
#pragma unroll
    for (int fm = 0; fm < 4; ++fm) {
#pragma unroll
      for (int fn = 0; fn < 4; ++fn) {
        const int col = n0 + wc * 64 + fn * 16 + fr;
        float* dst = trans +
            (size_t)(m0 + wr * 64 + fm * 16 + kg * 4) * DS2 + col;
#pragma unroll
        for (int r = 0; r < 4; ++r) {
          float v = ahh[fm][fn][r] + axx[fm][fn][r] * (1.0f / 2048.0f) +
                    all_[fm][fn][r] * (1.0f / 4194304.0f) + b2v[fn];
          dst[(size_t)r * DS2] = v;
        }
      }
    }
  }
}

// ---------------------------------------------------------------------------
// Standalone MLP kernel (chunk 0 priming)
// ---------------------------------------------------------------------------
__global__ __launch_bounds__(256) void k_mlp01(
    const float* __restrict__ actions, const float* __restrict__ w0,
    const float* __restrict__ b0, const float* __restrict__ w1,
    const float* __restrict__ b1, _Float16* __restrict__ h1h,
    _Float16* __restrict__ h1l, int s_base)
{
  __shared__ SharedMlp sm;
  mlp_tile(actions, w0, b0, w1, b1, h1h, h1l, s_base, blockIdx.x * 64, sm,
           threadIdx.x);
}

// ---------------------------------------------------------------------------
// Combined pipelined kernel, launch index c = 0..nch, grid 256 x 256 thr:
//  blocks 0..31  : rnn for chunk c-1 (if c>0) -- R8-VALIDATED direct-global
//                  consumer (1 wave, 2-deep register ping-pong prefetch).
//  blocks 32..255: MFMA trans tiles for chunk c (if c<nch), then mlp c+1.
// No spin-waits anywhere: all inter-phase dependencies are cross-launch.
// ---------------------------------------------------------------------------
__global__ __launch_bounds__(256, 1) void k_comb(
    const float* __restrict__ actions, const float* __restrict__ w0,
    const float* __restrict__ b0, const float* __restrict__ w1,
    const float* __restrict__ b1, const _Float16* __restrict__ w2h,
    const _Float16* __restrict__ w2l, const float* __restrict__ b2,
    const float* __restrict__ init_hidden,
    float* __restrict__ trans0, float* __restrict__ trans1,
    _Float16* __restrict__ h1h0, _Float16* __restrict__ h1l0,
    _Float16* __restrict__ h1h1, _Float16* __restrict__ h1l1,
    float* __restrict__ hstate, float* __restrict__ out,
    int c, int SC, int nch)
{
  __shared__ SharedU sh;
  const int tid = threadIdx.x;
  const int M = SC * 32;

  if (blockIdx.x >= 32) {
    // -------------------- GEMM blocks (224) --------------------
    const int x = blockIdx.x - 32;
    if (c < nch) {
      const _Float16* h1h = (c & 1) ? h1h1 : h1h0;
      const _Float16* h1l = (c & 1) ? h1l1 : h1l0;
      float* trans = (c & 1) ? trans1 : trans0;
      trans_loop(h1h, h1l, w2h, w2l, b2, trans, M / 128, x, sh.g, tid);
      if (c + 1 < nch) {
        __syncthreads();
        _Float16* hh = ((c + 1) & 1) ? h1h1 : h1h0;
        _Float16* hl = ((c + 1) & 1) ? h1l1 : h1l0;
        for (int j = x; j < M / 64; j += 224) {
          mlp_tile(actions, w0, b0, w1, b1, hh, hl, (c + 1) * SC, j * 64,
                   sh.m, tid);
          __syncthreads();
        }
      }
    }
    return;
  }

  // ---------------- RNN blocks (chunk c-1), R8-validated ------------------
  if (c == 0) return;
  if (tid >= 64) return;              // single consumer wave per block
  const int cc = c - 1;
  const float* trans = (cc & 1) ? trans1 : trans0;
  const int s_base = cc * SC;
  const int lane = tid;
  const int b = blockIdx.x;

  const int d = lane >> 4;
  const int cq = lane & 15;
  const bool d1 = (d & 1), d2 = (d & 2);
  const int pb = lane & 48;

  float4 hq;
  if (cc == 0) {
    hq = *(const float4*)(init_hidden + 4 * cq);
    float ss0 = row_sum16(hq.x * hq.x + hq.y * hq.y + hq.z * hq.z + hq.w * hq.w);
    float iv0 = 1.0f / fmaxf(sqrtf(ss0), 1e-12f);
    hq.x *= iv0; hq.y *= iv0; hq.z *= iv0; hq.w *= iv0;
  } else {
    hq = *(const float4*)(hstate + b * DS + 4 * cq);
  }
  float inv_prev = 1.0f;

  float* outp = out + ((size_t)b * S_ + s_base) * DS + 4 * cq;
  const float* g0 = trans + (size_t)b * DS2 + 4 * lane;
  const size_t sstride = (size_t)32 * DS2;

  auto step_fn = [&](const float4 (&T)[16], int s) {
    float hsel = d2 ? (d1 ? hq.w : hq.z) : (d1 ? hq.y : hq.x);
    float ax = 0.f, ay = 0.f, az = 0.f, aw = 0.f;
#pragma unroll
    for (int q = 0; q < 16; ++q) {
      float hb = __shfl(hsel, pb + q, 64);
      ax += hb * T[q].x; ay += hb * T[q].y;
      az += hb * T[q].z; aw += hb * T[q].w;
    }
    ax += __shfl_xor(ax, 16, 64); ax += __shfl_xor(ax, 32, 64);
    ay += __shfl_xor(ay, 16, 64); ay += __shfl_xor(ay, 32, 64);
    az += __shfl_xor(az, 16, 64); az += __shfl_xor(az, 32, 64);
    aw += __shfl_xor(aw, 16, 64); aw += __shfl_xor(aw, 32, 64);
    hq.x = fmaxf(ax * inv_prev, 0.f);
    hq.y = fmaxf(ay * inv_prev, 0.f);
    hq.z = fmaxf(az * inv_prev, 0.f);
    hq.w = fmaxf(aw * inv_prev, 0.f);
    float ss = row_sum16(hq.x * hq.x + hq.y * hq.y + hq.z * hq.z + hq.w * hq.w);
    float inv = 1.0f / fmaxf(sqrtf(ss), 1e-12f);
    if (d == 0) {
      float4 o;
      o.x = hq.x * inv; o.y = hq.y * inv; o.z = hq.z * inv; o.w = hq.w * inv;
      *(float4*)(outp + (size_t)s * DS) = o;
    }
    inv_prev = inv;
  };

  float4 A[16], Bv[16];
#pragma unroll
  for (int q = 0; q < 16; ++q) A[q] = *(const float4*)(g0 + q * 256);

  for (int s = 0; s < SC; s += 2) {
    const float* g1 = g0 + (size_t)(s + 1) * sstride;
#pragma unroll
    for (int q = 0; q < 16; ++q) Bv[q] = *(const float4*)(g1 + q * 256);
    step_fn(A, s);
    if (s + 2 < SC) {
      const float* g2 = g0 + (size_t)(s + 2) * sstride;
#pragma unroll
      for (int q = 0; q < 16; ++q) A[q] = *(const float4*)(g2 + q * 256);
    }
    step_fn(Bv, s + 1);
  }

  if (d == 0) {
    float4 o;   // carry NORMALIZED state across chunks
    o.x = hq.x * inv_prev; o.y = hq.y * inv_prev;
    o.z = hq.z * inv_prev; o.w = hq.w * inv_prev;
    *(float4*)(hstate + b * DS + 4 * cq) = o;
  }
}

// ---------------------------------------------------------------------------
extern "C" void kernel_launch(void* const* d_in, const int* in_sizes, int n_in,
                              void* d_out, int out_size, void* d_ws, size_t ws_size,
                              hipStream_t stream) {
  const float* actions     = (const float*)d_in[0];
  const float* w0          = (const float*)d_in[1];
  const float* b0          = (const float*)d_in[2];
  const float* w1          = (const float*)d_in[3];
  const float* b1          = (const float*)d_in[4];
  const float* w2          = (const float*)d_in[5];
  const float* b2          = (const float*)d_in[6];
  const float* init_hidden = (const float*)d_in[7];
  float* out = (float*)d_out;

  // largest chunk whose workspace fits:
  // 2x trans (f32) + 4x h1 split (f16) + 2x w2 split (f16) + hstate
  int SC = 2048;
  while (SC > 4) {
    size_t need = 2 * (size_t)SC * 32 * DS2 * 4
                + 4 * (size_t)SC * 32 * DH * 2
                + 2 * (size_t)DH * DS2 * 2
                + (size_t)B_ * DS * 4;
    if (need <= ws_size) break;
    SC >>= 1;
  }
  char* p = (char*)d_ws;
  float* trans0 = (float*)p;        p += (size_t)SC * 32 * DS2 * 4;
  float* trans1 = (float*)p;        p += (size_t)SC * 32 * DS2 * 4;
  _Float16* h1h0 = (_Float16*)p;    p += (size_t)SC * 32 * DH * 2;
  _Float16* h1l0 = (_Float16*)p;    p += (size_t)SC * 32 * DH * 2;
  _Float16* h1h1 = (_Float16*)p;    p += (size_t)SC * 32 * DH * 2;
  _Float16* h1l1 = (_Float16*)p;    p += (size_t)SC * 32 * DH * 2;
  _Float16* w2h  = (_Float16*)p;    p += (size_t)DH * DS2 * 2;
  _Float16* w2l  = (_Float16*)p;    p += (size_t)DH * DS2 * 2;
  float* hstate  = (float*)p;

  const int M = SC * 32;
  const int nch = S_ / SC;

  // prime: split w2 (once) and mlp for chunk 0 -> h1h0/h1l0
  hipLaunchKernelGGL(k_split, dim3(512), dim3(256), 0, stream, w2, w2h, w2l);
  hipLaunchKernelGGL(k_mlp01, dim3(M / 64), dim3(256), 0, stream,
                     actions, w0, b0, w1, b1, h1h0, h1l0, 0);
  // pipelined combined launches
  for (int c = 0; c <= nch; ++c) {
    hipLaunchKernelGGL(k_comb, dim3(256), dim3(256), 0, stream,
                       actions, w0, b0, w1, b1, w2h, w2l, b2, init_hidden,
                       trans0, trans1, h1h0, h1l0, h1h1, h1l1, hstate, out,
                       c, SC, nch);
  }
}